// Round 1
// baseline (1733.862 us; speedup 1.0000x reference)
//
#include <hip/hip_runtime.h>
#include <cstdint>
#include <cstddef>

typedef _Float16 f16;
typedef _Float16 f16x8 __attribute__((ext_vector_type(8)));
typedef float    fx4   __attribute__((ext_vector_type(4)));

// ---------------- elementwise prep ----------------

__device__ __forceinline__ float softplus_f(float x) {
    return (x > 20.0f) ? x : log1pf(expf(x));
}

// A = mw + softplus(sw)*zw -> f16 hi plane (+ optional lo residual plane)
__global__ void prep_w_kernel(const float* __restrict__ mw, const float* __restrict__ sw,
                              const float* __restrict__ zw, f16* __restrict__ hi,
                              f16* __restrict__ lo, int n) {
    int i = (blockIdx.x * blockDim.x + threadIdx.x) * 4;
    if (i >= n) return;
    float4 m4 = *(const float4*)(mw + i);
    float4 s4 = *(const float4*)(sw + i);
    float4 z4 = *(const float4*)(zw + i);
    float a[4];
    a[0] = m4.x + softplus_f(s4.x) * z4.x;
    a[1] = m4.y + softplus_f(s4.y) * z4.y;
    a[2] = m4.z + softplus_f(s4.z) * z4.z;
    a[3] = m4.w + softplus_f(s4.w) * z4.w;
    f16 h4[4], l4[4];
#pragma unroll
    for (int j = 0; j < 4; ++j) {
        h4[j] = (f16)a[j];
        l4[j] = (f16)(a[j] - (float)h4[j]);
    }
    *(short4*)(hi + i) = *(short4*)h4;
    if (lo) *(short4*)(lo + i) = *(short4*)l4;
}

__global__ void prep_b_kernel(const float* __restrict__ mb, const float* __restrict__ sb,
                              const float* __restrict__ zb, float* __restrict__ b, int n) {
    int i = blockIdx.x * blockDim.x + threadIdx.x;
    if (i < n) b[i] = mb[i] + softplus_f(sb[i]) * zb[i];
}

// split fp32 x into f16 hi + lo planes
__global__ void split_x_kernel(const float* __restrict__ x, f16* __restrict__ hi,
                               f16* __restrict__ lo, int n) {
    int i = (blockIdx.x * blockDim.x + threadIdx.x) * 4;
    if (i >= n) return;
    float4 v = *(const float4*)(x + i);
    float a[4] = {v.x, v.y, v.z, v.w};
    f16 h4[4], l4[4];
#pragma unroll
    for (int j = 0; j < 4; ++j) {
        h4[j] = (f16)a[j];
        l4[j] = (f16)(a[j] - (float)h4[j]);
    }
    *(short4*)(hi + i) = *(short4*)h4;
    *(short4*)(lo + i) = *(short4*)l4;
}

__device__ __forceinline__ void cp16(const f16* g, f16* l) {
    __builtin_amdgcn_global_load_lds((__attribute__((address_space(1))) void*)g,
                                     (__attribute__((address_space(3))) void*)l,
                                     16, 0, 0);
}

// ---------------- 256x256 ring-4 pipelined GEMM ----------------
// C[M,N] = H[M,K] @ W[N,K]^T (+bias, opt tanh).
// 8 waves (2M x 4N), per-wave 128x64 out. Ring of 4 K-slabs (BK=32),
// LDS = 4 slabs x (A 16KB + B 16KB) = 128 KiB.
// Pipeline: compute slab s from slot s&3 while slab s+3 streams into slot
// (s+3)&3 == (s-1)&3, whose reads finished before the slab-s barrier -> no WAR
// race. Counted vmcnt(8) (2 slabs * 4 loads in flight) -- never drains to 0 in
// steady state (T4). vmcnt is robust to extra interleaved loads (in-order
// retirement makes the bound only more conservative).
// LDS swizzle: slab stored as [row][chunk16B], chunk = kchunk ^ ((row>>1)&3).
// Reads spread uniformly over all 8 bank-groups (2-way max = free); writes go
// through linear-dest global_load_lds with the inverse permutation applied to
// the per-lane GLOBAL source (kc = (tid&3) ^ ((tid>>3)&3)).
// SPLIT=1: virtual-K stream K'=3K: slab pass p in {0,1,2} = Hh*Wh, Hh*Wl, Hl*Wh
// (same accumulation order as the previous 3-pass kernel).

template <int SPLIT, int OUT>
__global__ __launch_bounds__(512, 2) void gemm256_kernel(
    const f16* __restrict__ Hhi, const f16* __restrict__ Hlo,
    const f16* __restrict__ Whi, const f16* __restrict__ Wlo,
    const float* __restrict__ bias,
    f16* __restrict__ Ohi, f16* __restrict__ Olo, float* __restrict__ Of,
    int M, int N, int K)
{
    __shared__ __align__(16) f16 lds[4][2][8192];   // [slot][A/B][256 rows * 32 k]

    const int tid  = threadIdx.x;
    const int lane = tid & 63;
    const int wave = tid >> 6;
    const int wm   = wave >> 2;     // 0..1
    const int wn   = wave & 3;      // 0..3
    const int col  = lane & 15;
    const int quad = lane >> 4;

    // XCD-aware bijective block swizzle (all launches have nwg % 8 == 0)
    const int nwg = gridDim.x * gridDim.y;
    const int bid = blockIdx.y * gridDim.x + blockIdx.x;
    const int swz = (bid & 7) * (nwg >> 3) + (bid >> 3);
    const int bx  = swz % gridDim.x;
    const int by  = swz / gridDim.x;
    const int mBase = by * 256;
    const int nBase = bx * 256;

    // staging: thread t owns 16B chunks {t, t+512} of each slab-plane.
    // chunk c -> row c>>2, physical pos c&3, logical kchunk = pos ^ ((row>>1)&3)
    const int    srow = tid >> 2;                       // 0..127
    const int    kc   = (tid & 3) ^ ((tid >> 3) & 3);   // same for row and row+128
    const size_t aoff0 = (size_t)(mBase + srow) * K + kc * 8;
    const size_t aoff1 = aoff0 + (size_t)128 * K;
    const size_t boff0 = (size_t)(nBase + srow) * K + kc * 8;
    const size_t boff1 = boff0 + (size_t)128 * K;

    const int NT = (SPLIT ? 3 : 1) * (K >> 5);

    auto stageA = [&](int j) {
        const f16* src; int k0;
        if constexpr (SPLIT) { int kb = j / 3, p = j - kb * 3; src = (p == 2) ? Hlo : Hhi; k0 = kb * 32; }
        else                 { src = Hhi; k0 = j * 32; }
        f16* d = &lds[j & 3][0][0];
        cp16(src + aoff0 + k0, d + tid * 8);
        cp16(src + aoff1 + k0, d + tid * 8 + 4096);
    };
    auto stageB = [&](int j) {
        const f16* src; int k0;
        if constexpr (SPLIT) { int kb = j / 3, p = j - kb * 3; src = (p == 1) ? Wlo : Whi; k0 = kb * 32; }
        else                 { src = Whi; k0 = j * 32; }
        f16* d = &lds[j & 3][1][0];
        cp16(src + boff0 + k0, d + tid * 8);
        cp16(src + boff1 + k0, d + tid * 8 + 4096);
    };

    // prologue: 3 slabs in flight (12 loads/thread)
    stageA(0); stageB(0); stageA(1); stageB(1); stageA(2); stageB(2);

    float bias_v[4];
#pragma unroll
    for (int nf = 0; nf < 4; ++nf)
        bias_v[nf] = bias[nBase + wn * 64 + nf * 16 + col];

    fx4 acc[8][4];
#pragma unroll
    for (int i = 0; i < 8; ++i)
#pragma unroll
        for (int j = 0; j < 4; ++j)
            acc[i][j] = (fx4){0.f, 0.f, 0.f, 0.f};

    // fragment read: row = base + col, k-chunk = quad; swizzle key reduces to
    // (col>>1)&3 because base is a multiple of 16.
    const int lane_off = col * 32 + ((quad ^ ((col >> 1) & 3)) << 3);
    const int aRow = wm * 128;
    const int bRow = wn * 64;

    for (int s = 0; s < NT; ++s) {
        if (s < NT - 2)       asm volatile("s_waitcnt vmcnt(8)" ::: "memory");
        else if (s == NT - 2) asm volatile("s_waitcnt vmcnt(4)" ::: "memory");
        else                  asm volatile("s_waitcnt vmcnt(0)" ::: "memory");
        __builtin_amdgcn_s_barrier();

        const f16* As = &lds[s & 3][0][0];
        const f16* Bs = &lds[s & 3][1][0];

        f16x8 bfr[4], afr[4];
        // phase 0: all B frags + A quad 0, issue next A-stage, 16 MFMA
#pragma unroll
        for (int nf = 0; nf < 4; ++nf)
            bfr[nf] = *(const f16x8*)&Bs[(bRow + nf * 16) * 32 + lane_off];
#pragma unroll
        for (int mf = 0; mf < 4; ++mf)
            afr[mf] = *(const f16x8*)&As[(aRow + mf * 16) * 32 + lane_off];
        if (s + 3 < NT) stageA(s + 3);

        __builtin_amdgcn_s_setprio(1);
#pragma unroll
        for (int mf = 0; mf < 4; ++mf)
#pragma unroll
            for (int nf = 0; nf < 4; ++nf)
                acc[mf][nf] = __builtin_amdgcn_mfma_f32_16x16x32_f16(afr[mf], bfr[nf], acc[mf][nf], 0, 0, 0);
        __builtin_amdgcn_s_setprio(0);

        // phase 1: A quad 1, issue next B-stage, 16 MFMA
#pragma unroll
        for (int mf = 0; mf < 4; ++mf)
            afr[mf] = *(const f16x8*)&As[(aRow + 64 + mf * 16) * 32 + lane_off];
        if (s + 3 < NT) stageB(s + 3);

        __builtin_amdgcn_s_setprio(1);
#pragma unroll
        for (int mf = 0; mf < 4; ++mf)
#pragma unroll
            for (int nf = 0; nf < 4; ++nf)
                acc[4 + mf][nf] = __builtin_amdgcn_mfma_f32_16x16x32_f16(afr[mf], bfr[nf], acc[4 + mf][nf], 0, 0, 0);
        __builtin_amdgcn_s_setprio(0);
    }

    // epilogue: C row = quad*4 + r, col = lane&15 (m89-verified layout)
#pragma unroll
    for (int mf = 0; mf < 8; ++mf)
#pragma unroll
        for (int nf = 0; nf < 4; ++nf) {
            const int n = nBase + wn * 64 + nf * 16 + col;
#pragma unroll
            for (int r = 0; r < 4; ++r) {
                const int m = mBase + wm * 128 + mf * 16 + quad * 4 + r;
                float v = acc[mf][nf][r] + bias_v[nf];
                size_t idx = (size_t)m * N + n;
                if constexpr (OUT == 2) {
                    Of[idx] = v;
                } else {
                    float t = tanhf(v);
                    f16 thi = (f16)t;
                    Ohi[idx] = thi;
                    if constexpr (OUT == 1) Olo[idx] = (f16)(t - (float)thi);
                }
            }
        }
}

// ---------------- legacy 128x128 GEMM (kept for L3: N=1024 -> only 128
// 256-wide tiles would leave half the CUs idle; this one launches 512 wgs) ----

template <int SPLIT, int OUT>
__global__ __launch_bounds__(256) void gemm_kernel(
    const f16* __restrict__ Hhi, const f16* __restrict__ Hlo,
    const f16* __restrict__ Whi, const f16* __restrict__ Wlo,
    const float* __restrict__ bias,
    f16* __restrict__ Ohi, f16* __restrict__ Olo, float* __restrict__ Of,
    int M, int N, int K)
{
    constexpr int LDSN = 128 * 32;
    __shared__ __align__(16) f16 Hs[(SPLIT ? 2 : 1) * LDSN];
    __shared__ __align__(16) f16 Ws[(SPLIT ? 2 : 1) * LDSN];

    const int tid  = threadIdx.x;
    const int lane = tid & 63;
    const int wave = tid >> 6;
    const int wm   = wave >> 1;
    const int wn   = wave & 1;
    const int col  = lane & 15;
    const int quad = lane >> 4;
    const int mBase = blockIdx.y * 128;
    const int nBase = blockIdx.x * 128;

    float bias_v[4];
#pragma unroll
    for (int nt = 0; nt < 4; ++nt)
        bias_v[nt] = bias[nBase + wn * 64 + nt * 16 + col];

    fx4 acc[4][4];
#pragma unroll
    for (int i = 0; i < 4; ++i)
#pragma unroll
        for (int j = 0; j < 4; ++j)
            acc[i][j] = (fx4){0.f, 0.f, 0.f, 0.f};

    const int c0 = wave * 128 + lane;

    for (int k0 = 0; k0 < K; k0 += 32) {
        __syncthreads();
#pragma unroll
        for (int i = 0; i < 2; ++i) {
            int c  = c0 + i * 64;
            int r  = c >> 2;
            int cc = c & 3;
            size_t gh = (size_t)(mBase + r) * K + k0 + cc * 8;
            size_t gw = (size_t)(nBase + r) * K + k0 + cc * 8;
            cp16(Hhi + gh, &Hs[c * 8]);
            cp16(Whi + gw, &Ws[c * 8]);
            if constexpr (SPLIT) {
                cp16(Hlo + gh, &Hs[LDSN + c * 8]);
                cp16(Wlo + gw, &Ws[LDSN + c * 8]);
            }
        }
        __syncthreads();

        f16x8 bh[4], bl[4];
#pragma unroll
        for (int nt = 0; nt < 4; ++nt) {
            int off = (wn * 64 + nt * 16 + col) * 32 + quad * 8;
            bh[nt] = *(const f16x8*)&Ws[off];
            if constexpr (SPLIT) bl[nt] = *(const f16x8*)&Ws[LDSN + off];
        }
#pragma unroll
        for (int mt = 0; mt < 4; ++mt) {
            int off = (wm * 64 + mt * 16 + col) * 32 + quad * 8;
            f16x8 ah = *(const f16x8*)&Hs[off];
            f16x8 al;
            if constexpr (SPLIT) al = *(const f16x8*)&Hs[LDSN + off];
#pragma unroll
            for (int nt = 0; nt < 4; ++nt) {
                acc[mt][nt] = __builtin_amdgcn_mfma_f32_16x16x32_f16(ah, bh[nt], acc[mt][nt], 0, 0, 0);
                if constexpr (SPLIT) {
                    acc[mt][nt] = __builtin_amdgcn_mfma_f32_16x16x32_f16(ah, bl[nt], acc[mt][nt], 0, 0, 0);
                    acc[mt][nt] = __builtin_amdgcn_mfma_f32_16x16x32_f16(al, bh[nt], acc[mt][nt], 0, 0, 0);
                }
            }
        }
    }

#pragma unroll
    for (int mt = 0; mt < 4; ++mt) {
#pragma unroll
        for (int nt = 0; nt < 4; ++nt) {
            int n = nBase + wn * 64 + nt * 16 + col;
#pragma unroll
            for (int r = 0; r < 4; ++r) {
                int m = mBase + wm * 64 + mt * 16 + quad * 4 + r;
                float v = acc[mt][nt][r] + bias_v[nt];
                size_t idx = (size_t)m * N + n;
                if constexpr (OUT == 2) {
                    Of[idx] = v;
                } else {
                    float t = tanhf(v);
                    f16 thi = (f16)t;
                    Ohi[idx] = thi;
                    if constexpr (OUT == 1) Olo[idx] = (f16)(t - (float)thi);
                }
            }
        }
    }
}

// ---------------- host ----------------

extern "C" void kernel_launch(void* const* d_in, const int* in_sizes, int n_in,
                              void* d_out, int out_size, void* d_ws, size_t ws_size,
                              hipStream_t stream) {
    const int BATCH = 8192;
    const int sizes[5] = {1024, 4096, 4096, 4096, 1024};

    char* ws = (char*)d_ws;
    f16*   x_hi  = (f16*)(ws + 0);
    f16*   x_lo  = (f16*)(ws + 16777216ULL);
    f16*   A0_hi = (f16*)(ws + 33554432ULL);
    f16*   A0_lo = (f16*)(ws + 41943040ULL);
    f16*   A_hi  = (f16*)(ws + 0);
    f16*   A_lo  = (f16*)(ws + 33554432ULL);
    f16*   H0_hi = (f16*)(ws + 67108864ULL);
    f16*   H0_lo = (f16*)(ws + 134217728ULL);
    f16*   H1_hi = (f16*)(ws + 201326592ULL);
    f16*   H2_hi = (f16*)(ws + 67108864ULL);   // alias H0_hi (free after L1)
    float* bb    = (float*)(ws + 268435456ULL);

    const float* x = (const float*)d_in[0];
    const float* p[4][6];
    for (int j = 0; j < 4; ++j)
        for (int t = 0; t < 6; ++t)
            p[j][t] = (const float*)d_in[1 + j * 6 + t];

    {
        int n = BATCH * sizes[0];
        split_x_kernel<<<n / 4 / 256, 256, 0, stream>>>(x, x_hi, x_lo, n);
    }

    // ---- layer 0: [8192,1024] @ [4096,1024]^T, 3-pass split, out hi+lo ----
    {
        int n = sizes[1] * sizes[0];
        prep_w_kernel<<<n / 4 / 256, 256, 0, stream>>>(p[0][0], p[0][1], p[0][2], A0_hi, A0_lo, n);
        prep_b_kernel<<<(sizes[1] + 255) / 256, 256, 0, stream>>>(p[0][3], p[0][4], p[0][5], bb, sizes[1]);
        dim3 grid(sizes[1] / 256, BATCH / 256);
        gemm256_kernel<1, 1><<<grid, 512, 0, stream>>>(
            x_hi, x_lo, A0_hi, A0_lo, bb, H0_hi, H0_lo, nullptr, BATCH, sizes[1], sizes[0]);
    }

    // ---- layer 1: [8192,4096] @ [4096,4096]^T, 3-pass split, out hi ----
    {
        int n = sizes[2] * sizes[1];
        prep_w_kernel<<<n / 4 / 256, 256, 0, stream>>>(p[1][0], p[1][1], p[1][2], A_hi, A_lo, n);
        prep_b_kernel<<<(sizes[2] + 255) / 256, 256, 0, stream>>>(p[1][3], p[1][4], p[1][5], bb, sizes[2]);
        dim3 grid(sizes[2] / 256, BATCH / 256);
        gemm256_kernel<1, 0><<<grid, 512, 0, stream>>>(
            H0_hi, H0_lo, A_hi, A_lo, bb, H1_hi, nullptr, nullptr, BATCH, sizes[2], sizes[1]);
    }

    // ---- layer 2: [8192,4096] @ [4096,4096]^T, single pass, out hi ----
    {
        int n = sizes[3] * sizes[2];
        prep_w_kernel<<<n / 4 / 256, 256, 0, stream>>>(p[2][0], p[2][1], p[2][2], A_hi, nullptr, n);
        prep_b_kernel<<<(sizes[3] + 255) / 256, 256, 0, stream>>>(p[2][3], p[2][4], p[2][5], bb, sizes[3]);
        dim3 grid(sizes[3] / 256, BATCH / 256);
        gemm256_kernel<0, 0><<<grid, 512, 0, stream>>>(
            H1_hi, nullptr, A_hi, nullptr, bb, H2_hi, nullptr, nullptr, BATCH, sizes[3], sizes[2]);
    }

    // ---- layer 3: [8192,4096] @ [1024,4096]^T, single pass, fp32 out, no tanh ----
    {
        int n = sizes[4] * sizes[3];
        prep_w_kernel<<<n / 4 / 256, 256, 0, stream>>>(p[3][0], p[3][1], p[3][2], A_hi, nullptr, n);
        prep_b_kernel<<<(sizes[4] + 255) / 256, 256, 0, stream>>>(p[3][3], p[3][4], p[3][5], bb, sizes[4]);
        dim3 grid(sizes[4] / 128, BATCH / 128);
        gemm_kernel<0, 2><<<grid, 256, 0, stream>>>(
            H2_hi, nullptr, A_hi, nullptr, bb, nullptr, nullptr, (float*)d_out, BATCH, sizes[4], sizes[3]);
    }
}

// Round 2
// 1724.569 us; speedup vs baseline: 1.0054x; 1.0054x over previous
//
#include <hip/hip_runtime.h>
#include <cstdint>
#include <cstddef>

typedef _Float16 f16;
typedef _Float16 f16x8 __attribute__((ext_vector_type(8)));
typedef float    fx4   __attribute__((ext_vector_type(4)));

// ---------------- elementwise prep ----------------

__device__ __forceinline__ float softplus_f(float x) {
    return (x > 20.0f) ? x : log1pf(expf(x));
}

__global__ void prep_w_kernel(const float* __restrict__ mw, const float* __restrict__ sw,
                              const float* __restrict__ zw, f16* __restrict__ hi,
                              f16* __restrict__ lo, int n) {
    int i = (blockIdx.x * blockDim.x + threadIdx.x) * 4;
    if (i >= n) return;
    float4 m4 = *(const float4*)(mw + i);
    float4 s4 = *(const float4*)(sw + i);
    float4 z4 = *(const float4*)(zw + i);
    float a[4];
    a[0] = m4.x + softplus_f(s4.x) * z4.x;
    a[1] = m4.y + softplus_f(s4.y) * z4.y;
    a[2] = m4.z + softplus_f(s4.z) * z4.z;
    a[3] = m4.w + softplus_f(s4.w) * z4.w;
    f16 h4[4], l4[4];
#pragma unroll
    for (int j = 0; j < 4; ++j) {
        h4[j] = (f16)a[j];
        l4[j] = (f16)(a[j] - (float)h4[j]);
    }
    *(short4*)(hi + i) = *(short4*)h4;
    if (lo) *(short4*)(lo + i) = *(short4*)l4;
}

__global__ void prep_b_kernel(const float* __restrict__ mb, const float* __restrict__ sb,
                              const float* __restrict__ zb, float* __restrict__ b, int n) {
    int i = blockIdx.x * blockDim.x + threadIdx.x;
    if (i < n) b[i] = mb[i] + softplus_f(sb[i]) * zb[i];
}

__global__ void split_x_kernel(const float* __restrict__ x, f16* __restrict__ hi,
                               f16* __restrict__ lo, int n) {
    int i = (blockIdx.x * blockDim.x + threadIdx.x) * 4;
    if (i >= n) return;
    float4 v = *(const float4*)(x + i);
    float a[4] = {v.x, v.y, v.z, v.w};
    f16 h4[4], l4[4];
#pragma unroll
    for (int j = 0; j < 4; ++j) {
        h4[j] = (f16)a[j];
        l4[j] = (f16)(a[j] - (float)h4[j]);
    }
    *(short4*)(hi + i) = *(short4*)h4;
    *(short4*)(lo + i) = *(short4*)l4;
}

__device__ __forceinline__ void cp16(const f16* g, f16* l) {
    __builtin_amdgcn_global_load_lds((__attribute__((address_space(1))) void*)g,
                                     (__attribute__((address_space(3))) void*)l,
                                     16, 0, 0);
}

// ---------------- SPLIT GEMM: 4-plane ring-2, 3 phases/kb ----------------
// C = Hhi@Whi^T + Hhi@Wlo^T + Hlo@Whi^T (+bias, tanh) -- ~fp32 effective.
// 256x256 tile, 8 waves (2M x 4N), per-wave 128x64.
// LDS: 2 slots x 4 planes {Hh,Wh,Wl,Hl} x 16KB = 128 KiB.
// Per kb (K-chunk of 32): stage each plane ONCE (vs 6 half-stages in the old
// virtual-K stream); phases p0: Hh x Wh (reads Hh8+Wh4), p1: Hh x Wl (reads
// Wl4, A held in regs), p2: Hl x Wh (reads Hl8, B held in regs).
// LDS traffic/kb/CU: 24 reads x 8 waves + 64KB writes = 256KB (was 384KB) ->
// LDS-BW ceiling rises ~60% -> ~90% MfmaUtil.
// Counted vmcnt (issue order Hh,Wh,Wl,Hl; 8 loads/thread/kb):
//   entry: outstanding = this kb's 8 -> vmcnt(4) lands Hh+Wh
//   p1:    + next kb's 8 issued at p0 -> vmcnt(10) lands Wl
//   p2:    -> vmcnt(8) lands Hl      (tail peel: 4/2/0, no stage)
// Publication = own vmcnt + s_barrier; sched_barrier(0) pins reads below it.
// Accumulation order per element identical to the previous kernel (bit-exact).

#define PHASE_SYNC(V)                                          \
    asm volatile("s_waitcnt vmcnt(" V ")" ::: "memory");       \
    __builtin_amdgcn_s_barrier();                              \
    __builtin_amdgcn_sched_barrier(0);

template <int OUT>   // 0: f16 hi out (tanh), 1: f16 hi+lo out (tanh)
__global__ __launch_bounds__(512, 1) void gemm256_split3_kernel(
    const f16* __restrict__ Hhi, const f16* __restrict__ Hlo,
    const f16* __restrict__ Whi, const f16* __restrict__ Wlo,
    const float* __restrict__ bias,
    f16* __restrict__ Ohi, f16* __restrict__ Olo,
    int M, int N, int K)
{
    __shared__ __align__(16) f16 lds[2][4][8192];   // [slot][Hh,Wh,Wl,Hl][256r x 32k]

    const int tid  = threadIdx.x;
    const int lane = tid & 63;
    const int wave = tid >> 6;
    const int wm   = wave >> 2;     // 0..1
    const int wn   = wave & 3;      // 0..3
    const int col  = lane & 15;
    const int quad = lane >> 4;

    // XCD-aware bijective block swizzle (nwg % 8 == 0 for all launches)
    const int nwg = gridDim.x * gridDim.y;
    const int bid = blockIdx.y * gridDim.x + blockIdx.x;
    const int swz = (bid & 7) * (nwg >> 3) + (bid >> 3);
    const int bx  = swz % gridDim.x;
    const int by  = swz / gridDim.x;
    const int mBase = by * 256;
    const int nBase = bx * 256;

    // staging: thread t owns 16B chunks {t, t+512} of each plane.
    // chunk c -> row c>>2, physical pos c&3, logical kchunk = pos ^ ((row>>1)&3)
    const int    srow = tid >> 2;
    const int    kc   = (tid & 3) ^ ((tid >> 3) & 3);
    const size_t aoff0 = (size_t)(mBase + srow) * K + kc * 8;
    const size_t aoff1 = aoff0 + (size_t)128 * K;
    const size_t boff0 = (size_t)(nBase + srow) * K + kc * 8;
    const size_t boff1 = boff0 + (size_t)128 * K;

    const int NK = K >> 5;

    auto stage = [&](int j) {
        f16* d = &lds[j & 1][0][0];
        const int k0 = j * 32;
        cp16(Hhi + aoff0 + k0, d + tid * 8);                 // plane 0: Hh
        cp16(Hhi + aoff1 + k0, d + tid * 8 + 4096);
        cp16(Whi + boff0 + k0, d + 8192  + tid * 8);         // plane 1: Wh
        cp16(Whi + boff1 + k0, d + 8192  + tid * 8 + 4096);
        cp16(Wlo + boff0 + k0, d + 16384 + tid * 8);         // plane 2: Wl
        cp16(Wlo + boff1 + k0, d + 16384 + tid * 8 + 4096);
        cp16(Hlo + aoff0 + k0, d + 24576 + tid * 8);         // plane 3: Hl
        cp16(Hlo + aoff1 + k0, d + 24576 + tid * 8 + 4096);
    };

    float bias_v[4];
#pragma unroll
    for (int nf = 0; nf < 4; ++nf)
        bias_v[nf] = bias[nBase + wn * 64 + nf * 16 + col];

    stage(0);   // prologue: 8 loads in flight

    fx4 acc[8][4];
#pragma unroll
    for (int i = 0; i < 8; ++i)
#pragma unroll
        for (int j = 0; j < 4; ++j)
            acc[i][j] = (fx4){0.f, 0.f, 0.f, 0.f};

    // fragment read: row = base + col (base % 16 == 0), k-chunk = quad
    const int lane_off = col * 32 + ((quad ^ ((col >> 1) & 3)) << 3);
    const int aRow = wm * 128;
    const int bRow = wn * 64;

    f16x8 ah[8], bh[4], bl[4], al[8];

#define KB_BODY(V0, V1, V2, DO_STAGE, KB)                                          \
    {                                                                              \
        PHASE_SYNC(V0)                                                             \
        if (DO_STAGE) stage((KB) + 1);                                             \
        const f16* P = &lds[(KB) & 1][0][0];                                       \
        _Pragma("unroll")                                                          \
        for (int nf = 0; nf < 4; ++nf)                                             \
            bh[nf] = *(const f16x8*)&P[8192 + (bRow + nf * 16) * 32 + lane_off];   \
        _Pragma("unroll")                                                          \
        for (int mf = 0; mf < 8; ++mf)                                             \
            ah[mf] = *(const f16x8*)&P[(aRow + mf * 16) * 32 + lane_off];          \
        __builtin_amdgcn_s_setprio(1);                                             \
        _Pragma("unroll")                                                          \
        for (int mf = 0; mf < 8; ++mf)                                             \
            _Pragma("unroll")                                                      \
            for (int nf = 0; nf < 4; ++nf)                                         \
                acc[mf][nf] = __builtin_amdgcn_mfma_f32_16x16x32_f16(              \
                    ah[mf], bh[nf], acc[mf][nf], 0, 0, 0);                         \
        __builtin_amdgcn_s_setprio(0);                                             \
        PHASE_SYNC(V1)                                                             \
        _Pragma("unroll")                                                          \
        for (int nf = 0; nf < 4; ++nf)                                             \
            bl[nf] = *(const f16x8*)&P[16384 + (bRow + nf * 16) * 32 + lane_off];  \
        __builtin_amdgcn_s_setprio(1);                                             \
        _Pragma("unroll")                                                          \
        for (int mf = 0; mf < 8; ++mf)                                             \
            _Pragma("unroll")                                                      \
            for (int nf = 0; nf < 4; ++nf)                                         \
                acc[mf][nf] = __builtin_amdgcn_mfma_f32_16x16x32_f16(              \
                    ah[mf], bl[nf], acc[mf][nf], 0, 0, 0);                         \
        __builtin_amdgcn_s_setprio(0);                                             \
        PHASE_SYNC(V2)                                                             \
        _Pragma("unroll")                                                          \
        for (int mf = 0; mf < 8; ++mf)                                             \
            al[mf] = *(const f16x8*)&P[24576 + (aRow + mf * 16) * 32 + lane_off];  \
        __builtin_amdgcn_s_setprio(1);                                             \
        _Pragma("unroll")                                                          \
        for (int mf = 0; mf < 8; ++mf)                                             \
            _Pragma("unroll")                                                      \
            for (int nf = 0; nf < 4; ++nf)                                         \
                acc[mf][nf] = __builtin_amdgcn_mfma_f32_16x16x32_f16(              \
                    al[mf], bh[nf], acc[mf][nf], 0, 0, 0);                         \
        __builtin_amdgcn_s_setprio(0);                                             \
    }

    for (int kb = 0; kb + 1 < NK; ++kb)
        KB_BODY("4", "10", "8", true, kb)
    KB_BODY("4", "2", "0", false, NK - 1)   // tail: nothing left in flight

#undef KB_BODY

    // epilogue: C row = quad*4 + r, col = lane&15 (m89-verified layout)
#pragma unroll
    for (int mf = 0; mf < 8; ++mf)
#pragma unroll
        for (int nf = 0; nf < 4; ++nf) {
            const int n = nBase + wn * 64 + nf * 16 + col;
#pragma unroll
            for (int r = 0; r < 4; ++r) {
                const int m = mBase + wm * 128 + mf * 16 + quad * 4 + r;
                float v = acc[mf][nf][r] + bias_v[nf];
                size_t idx = (size_t)m * N + n;
                float t = tanhf(v);
                f16 thi = (f16)t;
                Ohi[idx] = thi;
                if constexpr (OUT == 1) Olo[idx] = (f16)(t - (float)thi);
            }
        }
}

// ---------------- non-split 256x256 ring-4 pipelined GEMM (L2) ----------------

template <int SPLIT, int OUT>
__global__ __launch_bounds__(512, 2) void gemm256_kernel(
    const f16* __restrict__ Hhi, const f16* __restrict__ Hlo,
    const f16* __restrict__ Whi, const f16* __restrict__ Wlo,
    const float* __restrict__ bias,
    f16* __restrict__ Ohi, f16* __restrict__ Olo, float* __restrict__ Of,
    int M, int N, int K)
{
    __shared__ __align__(16) f16 lds[4][2][8192];   // [slot][A/B][256 rows * 32 k]

    const int tid  = threadIdx.x;
    const int lane = tid & 63;
    const int wave = tid >> 6;
    const int wm   = wave >> 2;     // 0..1
    const int wn   = wave & 3;      // 0..3
    const int col  = lane & 15;
    const int quad = lane >> 4;

    const int nwg = gridDim.x * gridDim.y;
    const int bid = blockIdx.y * gridDim.x + blockIdx.x;
    const int swz = (bid & 7) * (nwg >> 3) + (bid >> 3);
    const int bx  = swz % gridDim.x;
    const int by  = swz / gridDim.x;
    const int mBase = by * 256;
    const int nBase = bx * 256;

    const int    srow = tid >> 2;
    const int    kc   = (tid & 3) ^ ((tid >> 3) & 3);
    const size_t aoff0 = (size_t)(mBase + srow) * K + kc * 8;
    const size_t aoff1 = aoff0 + (size_t)128 * K;
    const size_t boff0 = (size_t)(nBase + srow) * K + kc * 8;
    const size_t boff1 = boff0 + (size_t)128 * K;

    const int NT = K >> 5;

    auto stageA = [&](int j) {
        f16* d = &lds[j & 3][0][0];
        cp16(Hhi + aoff0 + j * 32, d + tid * 8);
        cp16(Hhi + aoff1 + j * 32, d + tid * 8 + 4096);
    };
    auto stageB = [&](int j) {
        f16* d = &lds[j & 3][1][0];
        cp16(Whi + boff0 + j * 32, d + tid * 8);
        cp16(Whi + boff1 + j * 32, d + tid * 8 + 4096);
    };

    stageA(0); stageB(0); stageA(1); stageB(1); stageA(2); stageB(2);

    float bias_v[4];
#pragma unroll
    for (int nf = 0; nf < 4; ++nf)
        bias_v[nf] = bias[nBase + wn * 64 + nf * 16 + col];

    fx4 acc[8][4];
#pragma unroll
    for (int i = 0; i < 8; ++i)
#pragma unroll
        for (int j = 0; j < 4; ++j)
            acc[i][j] = (fx4){0.f, 0.f, 0.f, 0.f};

    const int lane_off = col * 32 + ((quad ^ ((col >> 1) & 3)) << 3);
    const int aRow = wm * 128;
    const int bRow = wn * 64;

    for (int s = 0; s < NT; ++s) {
        if (s < NT - 2)       asm volatile("s_waitcnt vmcnt(8)" ::: "memory");
        else if (s == NT - 2) asm volatile("s_waitcnt vmcnt(4)" ::: "memory");
        else                  asm volatile("s_waitcnt vmcnt(0)" ::: "memory");
        __builtin_amdgcn_s_barrier();
        __builtin_amdgcn_sched_barrier(0);

        const f16* As = &lds[s & 3][0][0];
        const f16* Bs = &lds[s & 3][1][0];

        f16x8 bfr[4], afr[4];
#pragma unroll
        for (int nf = 0; nf < 4; ++nf)
            bfr[nf] = *(const f16x8*)&Bs[(bRow + nf * 16) * 32 + lane_off];
#pragma unroll
        for (int mf = 0; mf < 4; ++mf)
            afr[mf] = *(const f16x8*)&As[(aRow + mf * 16) * 32 + lane_off];
        if (s + 3 < NT) stageA(s + 3);

        __builtin_amdgcn_s_setprio(1);
#pragma unroll
        for (int mf = 0; mf < 4; ++mf)
#pragma unroll
            for (int nf = 0; nf < 4; ++nf)
                acc[mf][nf] = __builtin_amdgcn_mfma_f32_16x16x32_f16(afr[mf], bfr[nf], acc[mf][nf], 0, 0, 0);
        __builtin_amdgcn_s_setprio(0);

#pragma unroll
        for (int mf = 0; mf < 4; ++mf)
            afr[mf] = *(const f16x8*)&As[(aRow + 64 + mf * 16) * 32 + lane_off];
        if (s + 3 < NT) stageB(s + 3);

        __builtin_amdgcn_s_setprio(1);
#pragma unroll
        for (int mf = 0; mf < 4; ++mf)
#pragma unroll
            for (int nf = 0; nf < 4; ++nf)
                acc[4 + mf][nf] = __builtin_amdgcn_mfma_f32_16x16x32_f16(afr[mf], bfr[nf], acc[4 + mf][nf], 0, 0, 0);
        __builtin_amdgcn_s_setprio(0);
    }

#pragma unroll
    for (int mf = 0; mf < 8; ++mf)
#pragma unroll
        for (int nf = 0; nf < 4; ++nf) {
            const int n = nBase + wn * 64 + nf * 16 + col;
#pragma unroll
            for (int r = 0; r < 4; ++r) {
                const int m = mBase + wm * 128 + mf * 16 + quad * 4 + r;
                float v = acc[mf][nf][r] + bias_v[nf];
                size_t idx = (size_t)m * N + n;
                if constexpr (OUT == 2) {
                    Of[idx] = v;
                } else {
                    float t = tanhf(v);
                    f16 thi = (f16)t;
                    Ohi[idx] = thi;
                    if constexpr (OUT == 1) Olo[idx] = (f16)(t - (float)thi);
                }
            }
        }
}

// ---------------- legacy 128x128 GEMM (L3: N=1024 -> 512 wgs) ----------------

template <int SPLIT, int OUT>
__global__ __launch_bounds__(256) void gemm_kernel(
    const f16* __restrict__ Hhi, const f16* __restrict__ Hlo,
    const f16* __restrict__ Whi, const f16* __restrict__ Wlo,
    const float* __restrict__ bias,
    f16* __restrict__ Ohi, f16* __restrict__ Olo, float* __restrict__ Of,
    int M, int N, int K)
{
    constexpr int LDSN = 128 * 32;
    __shared__ __align__(16) f16 Hs[(SPLIT ? 2 : 1) * LDSN];
    __shared__ __align__(16) f16 Ws[(SPLIT ? 2 : 1) * LDSN];

    const int tid  = threadIdx.x;
    const int lane = tid & 63;
    const int wave = tid >> 6;
    const int wm   = wave >> 1;
    const int wn   = wave & 1;
    const int col  = lane & 15;
    const int quad = lane >> 4;
    const int mBase = blockIdx.y * 128;
    const int nBase = blockIdx.x * 128;

    float bias_v[4];
#pragma unroll
    for (int nt = 0; nt < 4; ++nt)
        bias_v[nt] = bias[nBase + wn * 64 + nt * 16 + col];

    fx4 acc[4][4];
#pragma unroll
    for (int i = 0; i < 4; ++i)
#pragma unroll
        for (int j = 0; j < 4; ++j)
            acc[i][j] = (fx4){0.f, 0.f, 0.f, 0.f};

    const int c0 = wave * 128 + lane;

    for (int k0 = 0; k0 < K; k0 += 32) {
        __syncthreads();
#pragma unroll
        for (int i = 0; i < 2; ++i) {
            int c  = c0 + i * 64;
            int r  = c >> 2;
            int cc = c & 3;
            size_t gh = (size_t)(mBase + r) * K + k0 + cc * 8;
            size_t gw = (size_t)(nBase + r) * K + k0 + cc * 8;
            cp16(Hhi + gh, &Hs[c * 8]);
            cp16(Whi + gw, &Ws[c * 8]);
            if constexpr (SPLIT) {
                cp16(Hlo + gh, &Hs[LDSN + c * 8]);
                cp16(Wlo + gw, &Ws[LDSN + c * 8]);
            }
        }
        __syncthreads();

        f16x8 bh[4], bl[4];
#pragma unroll
        for (int nt = 0; nt < 4; ++nt) {
            int off = (wn * 64 + nt * 16 + col) * 32 + quad * 8;
            bh[nt] = *(const f16x8*)&Ws[off];
            if constexpr (SPLIT) bl[nt] = *(const f16x8*)&Ws[LDSN + off];
        }
#pragma unroll
        for (int mt = 0; mt < 4; ++mt) {
            int off = (wm * 64 + mt * 16 + col) * 32 + quad * 8;
            f16x8 ah = *(const f16x8*)&Hs[off];
            f16x8 al;
            if constexpr (SPLIT) al = *(const f16x8*)&Hs[LDSN + off];
#pragma unroll
            for (int nt = 0; nt < 4; ++nt) {
                acc[mt][nt] = __builtin_amdgcn_mfma_f32_16x16x32_f16(ah, bh[nt], acc[mt][nt], 0, 0, 0);
                if constexpr (SPLIT) {
                    acc[mt][nt] = __builtin_amdgcn_mfma_f32_16x16x32_f16(ah, bl[nt], acc[mt][nt], 0, 0, 0);
                    acc[mt][nt] = __builtin_amdgcn_mfma_f32_16x16x32_f16(al, bh[nt], acc[mt][nt], 0, 0, 0);
                }
            }
        }
    }

#pragma unroll
    for (int mt = 0; mt < 4; ++mt) {
#pragma unroll
        for (int nt = 0; nt < 4; ++nt) {
            int n = nBase + wn * 64 + nt * 16 + col;
#pragma unroll
            for (int r = 0; r < 4; ++r) {
                int m = mBase + wm * 64 + mt * 16 + quad * 4 + r;
                float v = acc[mt][nt][r] + bias_v[nt];
                size_t idx = (size_t)m * N + n;
                if constexpr (OUT == 2) {
                    Of[idx] = v;
                } else {
                    float t = tanhf(v);
                    f16 thi = (f16)t;
                    Ohi[idx] = thi;
                    if constexpr (OUT == 1) Olo[idx] = (f16)(t - (float)thi);
                }
            }
        }
    }
}

// ---------------- host ----------------

extern "C" void kernel_launch(void* const* d_in, const int* in_sizes, int n_in,
                              void* d_out, int out_size, void* d_ws, size_t ws_size,
                              hipStream_t stream) {
    const int BATCH = 8192;
    const int sizes[5] = {1024, 4096, 4096, 4096, 1024};

    char* ws = (char*)d_ws;
    f16*   x_hi  = (f16*)(ws + 0);
    f16*   x_lo  = (f16*)(ws + 16777216ULL);
    f16*   A0_hi = (f16*)(ws + 33554432ULL);
    f16*   A0_lo = (f16*)(ws + 41943040ULL);
    f16*   A_hi  = (f16*)(ws + 0);
    f16*   A_lo  = (f16*)(ws + 33554432ULL);
    f16*   H0_hi = (f16*)(ws + 67108864ULL);
    f16*   H0_lo = (f16*)(ws + 134217728ULL);
    f16*   H1_hi = (f16*)(ws + 201326592ULL);
    f16*   H2_hi = (f16*)(ws + 67108864ULL);   // alias H0_hi (free after L1)
    float* bb    = (float*)(ws + 268435456ULL);

    const float* x = (const float*)d_in[0];
    const float* p[4][6];
    for (int j = 0; j < 4; ++j)
        for (int t = 0; t < 6; ++t)
            p[j][t] = (const float*)d_in[1 + j * 6 + t];

    {
        int n = BATCH * sizes[0];
        split_x_kernel<<<n / 4 / 256, 256, 0, stream>>>(x, x_hi, x_lo, n);
    }

    // ---- layer 0: [8192,1024] @ [4096,1024]^T, 4-plane split, out hi+lo ----
    {
        int n = sizes[1] * sizes[0];
        prep_w_kernel<<<n / 4 / 256, 256, 0, stream>>>(p[0][0], p[0][1], p[0][2], A0_hi, A0_lo, n);
        prep_b_kernel<<<(sizes[1] + 255) / 256, 256, 0, stream>>>(p[0][3], p[0][4], p[0][5], bb, sizes[1]);
        dim3 grid(sizes[1] / 256, BATCH / 256);
        gemm256_split3_kernel<1><<<grid, 512, 0, stream>>>(
            x_hi, x_lo, A0_hi, A0_lo, bb, H0_hi, H0_lo, BATCH, sizes[1], sizes[0]);
    }

    // ---- layer 1: [8192,4096] @ [4096,4096]^T, 4-plane split, out hi ----
    {
        int n = sizes[2] * sizes[1];
        prep_w_kernel<<<n / 4 / 256, 256, 0, stream>>>(p[1][0], p[1][1], p[1][2], A_hi, A_lo, n);
        prep_b_kernel<<<(sizes[2] + 255) / 256, 256, 0, stream>>>(p[1][3], p[1][4], p[1][5], bb, sizes[2]);
        dim3 grid(sizes[2] / 256, BATCH / 256);
        gemm256_split3_kernel<0><<<grid, 512, 0, stream>>>(
            H0_hi, H0_lo, A_hi, A_lo, bb, H1_hi, nullptr, BATCH, sizes[2], sizes[1]);
    }

    // ---- layer 2: [8192,4096] @ [4096,4096]^T, single pass, out hi ----
    {
        int n = sizes[3] * sizes[2];
        prep_w_kernel<<<n / 4 / 256, 256, 0, stream>>>(p[2][0], p[2][1], p[2][2], A_hi, nullptr, n);
        prep_b_kernel<<<(sizes[3] + 255) / 256, 256, 0, stream>>>(p[2][3], p[2][4], p[2][5], bb, sizes[3]);
        dim3 grid(sizes[3] / 256, BATCH / 256);
        gemm256_kernel<0, 0><<<grid, 512, 0, stream>>>(
            H1_hi, nullptr, A_hi, nullptr, bb, H2_hi, nullptr, nullptr, BATCH, sizes[3], sizes[2]);
    }

    // ---- layer 3: [8192,4096] @ [1024,4096]^T, single pass, fp32 out, no tanh ----
    {
        int n = sizes[4] * sizes[3];
        prep_w_kernel<<<n / 4 / 256, 256, 0, stream>>>(p[3][0], p[3][1], p[3][2], A_hi, nullptr, n);
        prep_b_kernel<<<(sizes[4] + 255) / 256, 256, 0, stream>>>(p[3][3], p[3][4], p[3][5], bb, sizes[4]);
        dim3 grid(sizes[4] / 128, BATCH / 128);
        gemm_kernel<0, 2><<<grid, 256, 0, stream>>>(
            H2_hi, nullptr, A_hi, nullptr, bb, nullptr, nullptr, (float*)d_out, BATCH, sizes[4], sizes[3]);
    }
}

// Round 3
// 1710.374 us; speedup vs baseline: 1.0137x; 1.0083x over previous
//
#include <hip/hip_runtime.h>
#include <cstdint>
#include <cstddef>

typedef _Float16 f16;
typedef _Float16 f16x8 __attribute__((ext_vector_type(8)));
typedef float    fx4   __attribute__((ext_vector_type(4)));

// ---------------- elementwise prep ----------------

__device__ __forceinline__ float softplus_f(float x) {
    return (x > 20.0f) ? x : log1pf(expf(x));
}

__global__ void prep_w_kernel(const float* __restrict__ mw, const float* __restrict__ sw,
                              const float* __restrict__ zw, f16* __restrict__ hi,
                              f16* __restrict__ lo, int n) {
    int i = (blockIdx.x * blockDim.x + threadIdx.x) * 4;
    if (i >= n) return;
    float4 m4 = *(const float4*)(mw + i);
    float4 s4 = *(const float4*)(sw + i);
    float4 z4 = *(const float4*)(zw + i);
    float a[4];
    a[0] = m4.x + softplus_f(s4.x) * z4.x;
    a[1] = m4.y + softplus_f(s4.y) * z4.y;
    a[2] = m4.z + softplus_f(s4.z) * z4.z;
    a[3] = m4.w + softplus_f(s4.w) * z4.w;
    f16 h4[4], l4[4];
#pragma unroll
    for (int j = 0; j < 4; ++j) {
        h4[j] = (f16)a[j];
        l4[j] = (f16)(a[j] - (float)h4[j]);
    }
    *(short4*)(hi + i) = *(short4*)h4;
    if (lo) *(short4*)(lo + i) = *(short4*)l4;
}

__global__ void prep_b_kernel(const float* __restrict__ mb, const float* __restrict__ sb,
                              const float* __restrict__ zb, float* __restrict__ b, int n) {
    int i = blockIdx.x * blockDim.x + threadIdx.x;
    if (i < n) b[i] = mb[i] + softplus_f(sb[i]) * zb[i];
}

__global__ void split_x_kernel(const float* __restrict__ x, f16* __restrict__ hi,
                               f16* __restrict__ lo, int n) {
    int i = (blockIdx.x * blockDim.x + threadIdx.x) * 4;
    if (i >= n) return;
    float4 v = *(const float4*)(x + i);
    float a[4] = {v.x, v.y, v.z, v.w};
    f16 h4[4], l4[4];
#pragma unroll
    for (int j = 0; j < 4; ++j) {
        h4[j] = (f16)a[j];
        l4[j] = (f16)(a[j] - (float)h4[j]);
    }
    *(short4*)(hi + i) = *(short4*)h4;
    *(short4*)(lo + i) = *(short4*)l4;
}

__device__ __forceinline__ void cp16(const f16* g, f16* l) {
    __builtin_amdgcn_global_load_lds((__attribute__((address_space(1))) void*)g,
                                     (__attribute__((address_space(3))) void*)l,
                                     16, 0, 0);
}

// ---------------- SPLIT GEMM: 4-plane ring-2, ONE barrier per kb ----------------
// C = Hhi@Whi^T + Hhi@Wlo^T + Hlo@Whi^T (+bias, tanh) -- ~fp32 effective.
// 256x256 tile, 8 waves (2M x 4N), per-wave 128x64.
// LDS: 2 slots x 4 planes {Hh,Wh,Wl,Hl} x 16KB = 128 KiB.
// R2 lesson: mid-kb barriers lockstep all waves into {barrier -> reads ->
// lgkm-wait -> MFMA}: every phase exposes the full LDS read latency on all
// SIMDs at once -> MfmaUtil caps ~51% regardless of traffic. Fix: publish ALL
// planes at ONE kb-entry barrier (vmcnt(0) is nearly free: the waited loads
// were issued a whole kb body earlier), then run the 96-MFMA body barrier-free
// with all 24 fragment reads issued up-front. p1/p2 fragments land under p0's
// MFMA (fine-grained lgkmcnt), and waves drift out of lockstep -> cross-wave
// LDS/MFMA overlap.
// Race check: stage(kb+1) targets the OTHER slot and is issued after the entry
// barrier, by which point every wave's kb-1 reads are register-resident (their
// MFMAs consumed them) -> no WAR. Per-element accumulation order unchanged
// (AhBh, AhBl, AlBh per kb) -> bit-identical results.

template <int OUT>   // 0: f16 hi out (tanh), 1: f16 hi+lo out (tanh)
__global__ __launch_bounds__(512, 1) void gemm256_split3_kernel(
    const f16* __restrict__ Hhi, const f16* __restrict__ Hlo,
    const f16* __restrict__ Whi, const f16* __restrict__ Wlo,
    const float* __restrict__ bias,
    f16* __restrict__ Ohi, f16* __restrict__ Olo,
    int M, int N, int K)
{
    __shared__ __align__(16) f16 lds[2][4][8192];   // [slot][Hh,Wh,Wl,Hl][256r x 32k]

    const int tid  = threadIdx.x;
    const int lane = tid & 63;
    const int wave = tid >> 6;
    const int wm   = wave >> 2;     // 0..1
    const int wn   = wave & 3;      // 0..3
    const int col  = lane & 15;
    const int quad = lane >> 4;

    // XCD-aware bijective block swizzle (nwg % 8 == 0 for all launches)
    const int nwg = gridDim.x * gridDim.y;
    const int bid = blockIdx.y * gridDim.x + blockIdx.x;
    const int swz = (bid & 7) * (nwg >> 3) + (bid >> 3);
    const int bx  = swz % gridDim.x;
    const int by  = swz / gridDim.x;
    const int mBase = by * 256;
    const int nBase = bx * 256;

    // staging: thread t owns 16B chunks {t, t+512} of each plane.
    // chunk c -> row c>>2, physical pos c&3, logical kchunk = pos ^ ((row>>1)&3)
    const int    srow = tid >> 2;
    const int    kc   = (tid & 3) ^ ((tid >> 3) & 3);
    const size_t aoff0 = (size_t)(mBase + srow) * K + kc * 8;
    const size_t aoff1 = aoff0 + (size_t)128 * K;
    const size_t boff0 = (size_t)(nBase + srow) * K + kc * 8;
    const size_t boff1 = boff0 + (size_t)128 * K;

    const int NK = K >> 5;

    auto stage = [&](int j) {
        f16* d = &lds[j & 1][0][0];
        const int k0 = j * 32;
        cp16(Hhi + aoff0 + k0, d + tid * 8);                 // plane 0: Hh
        cp16(Hhi + aoff1 + k0, d + tid * 8 + 4096);
        cp16(Whi + boff0 + k0, d + 8192  + tid * 8);         // plane 1: Wh
        cp16(Whi + boff1 + k0, d + 8192  + tid * 8 + 4096);
        cp16(Wlo + boff0 + k0, d + 16384 + tid * 8);         // plane 2: Wl
        cp16(Wlo + boff1 + k0, d + 16384 + tid * 8 + 4096);
        cp16(Hlo + aoff0 + k0, d + 24576 + tid * 8);         // plane 3: Hl
        cp16(Hlo + aoff1 + k0, d + 24576 + tid * 8 + 4096);
    };

    float bias_v[4];
#pragma unroll
    for (int nf = 0; nf < 4; ++nf)
        bias_v[nf] = bias[nBase + wn * 64 + nf * 16 + col];

    stage(0);   // prologue: 8 loads in flight

    fx4 acc[8][4];
#pragma unroll
    for (int i = 0; i < 8; ++i)
#pragma unroll
        for (int j = 0; j < 4; ++j)
            acc[i][j] = (fx4){0.f, 0.f, 0.f, 0.f};

    // fragment read: row = base + col (base % 16 == 0), k-chunk = quad
    const int lane_off = col * 32 + ((quad ^ ((col >> 1) & 3)) << 3);
    const int aRow = wm * 128;
    const int bRow = wn * 64;

    for (int kb = 0; kb < NK; ++kb) {
        // entry sync: own 8 loads of slot kb (issued one kb ago) + all-thread
        // publication. Only barrier in the loop.
        asm volatile("s_waitcnt vmcnt(0)" ::: "memory");
        __builtin_amdgcn_s_barrier();
        __builtin_amdgcn_sched_barrier(0);

        if (kb + 1 < NK) stage(kb + 1);

        const f16* P = &lds[kb & 1][0][0];
        f16x8 ah[8], bh[4], bl[4], al[8];
#pragma unroll
        for (int nf = 0; nf < 4; ++nf)
            bh[nf] = *(const f16x8*)&P[8192 + (bRow + nf * 16) * 32 + lane_off];
#pragma unroll
        for (int mf = 0; mf < 8; ++mf)
            ah[mf] = *(const f16x8*)&P[(aRow + mf * 16) * 32 + lane_off];
#pragma unroll
        for (int nf = 0; nf < 4; ++nf)
            bl[nf] = *(const f16x8*)&P[16384 + (bRow + nf * 16) * 32 + lane_off];
#pragma unroll
        for (int mf = 0; mf < 8; ++mf)
            al[mf] = *(const f16x8*)&P[24576 + (aRow + mf * 16) * 32 + lane_off];

        // p0: Hh x Wh
        __builtin_amdgcn_s_setprio(1);
#pragma unroll
        for (int mf = 0; mf < 8; ++mf)
#pragma unroll
            for (int nf = 0; nf < 4; ++nf)
                acc[mf][nf] = __builtin_amdgcn_mfma_f32_16x16x32_f16(ah[mf], bh[nf], acc[mf][nf], 0, 0, 0);
        __builtin_amdgcn_s_setprio(0);

        // p1: Hh x Wl
        __builtin_amdgcn_s_setprio(1);
#pragma unroll
        for (int mf = 0; mf < 8; ++mf)
#pragma unroll
            for (int nf = 0; nf < 4; ++nf)
                acc[mf][nf] = __builtin_amdgcn_mfma_f32_16x16x32_f16(ah[mf], bl[nf], acc[mf][nf], 0, 0, 0);
        __builtin_amdgcn_s_setprio(0);

        // p2: Hl x Wh
        __builtin_amdgcn_s_setprio(1);
#pragma unroll
        for (int mf = 0; mf < 8; ++mf)
#pragma unroll
            for (int nf = 0; nf < 4; ++nf)
                acc[mf][nf] = __builtin_amdgcn_mfma_f32_16x16x32_f16(al[mf], bh[nf], acc[mf][nf], 0, 0, 0);
        __builtin_amdgcn_s_setprio(0);
    }

    // epilogue: C row = quad*4 + r, col = lane&15 (m89-verified layout)
#pragma unroll
    for (int mf = 0; mf < 8; ++mf)
#pragma unroll
        for (int nf = 0; nf < 4; ++nf) {
            const int n = nBase + wn * 64 + nf * 16 + col;
#pragma unroll
            for (int r = 0; r < 4; ++r) {
                const int m = mBase + wm * 128 + mf * 16 + quad * 4 + r;
                float v = acc[mf][nf][r] + bias_v[nf];
                size_t idx = (size_t)m * N + n;
                float t = tanhf(v);
                f16 thi = (f16)t;
                Ohi[idx] = thi;
                if constexpr (OUT == 1) Olo[idx] = (f16)(t - (float)thi);
            }
        }
}

// ---------------- non-split GEMM: 2-plane ring-2, ONE barrier per kb ----------
// 256x256 tile, 8 waves, LDS = 2 slots x (A 16KB + B 16KB) = 64 KiB ->
// 2 blocks/CU: the entry vmcnt(0)+barrier of one block overlaps the other
// block's MFMA body (cross-block pipe overlap the single-block split3 lacks).

template <int OUT>   // 0: f16 hi out (tanh), 2: fp32 out (no tanh)
__global__ __launch_bounds__(512, 2) void gemm256_ns_kernel(
    const f16* __restrict__ Hhi, const f16* __restrict__ Whi,
    const float* __restrict__ bias,
    f16* __restrict__ Ohi, float* __restrict__ Of,
    int M, int N, int K)
{
    __shared__ __align__(16) f16 lds[2][2][8192];   // [slot][A,B][256r x 32k]

    const int tid  = threadIdx.x;
    const int lane = tid & 63;
    const int wave = tid >> 6;
    const int wm   = wave >> 2;
    const int wn   = wave & 3;
    const int col  = lane & 15;
    const int quad = lane >> 4;

    const int nwg = gridDim.x * gridDim.y;
    const int bid = blockIdx.y * gridDim.x + blockIdx.x;
    const int swz = (bid & 7) * (nwg >> 3) + (bid >> 3);
    const int bx  = swz % gridDim.x;
    const int by  = swz / gridDim.x;
    const int mBase = by * 256;
    const int nBase = bx * 256;

    const int    srow = tid >> 2;
    const int    kc   = (tid & 3) ^ ((tid >> 3) & 3);
    const size_t aoff0 = (size_t)(mBase + srow) * K + kc * 8;
    const size_t aoff1 = aoff0 + (size_t)128 * K;
    const size_t boff0 = (size_t)(nBase + srow) * K + kc * 8;
    const size_t boff1 = boff0 + (size_t)128 * K;

    const int NK = K >> 5;

    auto stage = [&](int j) {
        f16* d = &lds[j & 1][0][0];
        const int k0 = j * 32;
        cp16(Hhi + aoff0 + k0, d + tid * 8);
        cp16(Hhi + aoff1 + k0, d + tid * 8 + 4096);
        cp16(Whi + boff0 + k0, d + 8192 + tid * 8);
        cp16(Whi + boff1 + k0, d + 8192 + tid * 8 + 4096);
    };

    float bias_v[4];
#pragma unroll
    for (int nf = 0; nf < 4; ++nf)
        bias_v[nf] = bias[nBase + wn * 64 + nf * 16 + col];

    stage(0);

    fx4 acc[8][4];
#pragma unroll
    for (int i = 0; i < 8; ++i)
#pragma unroll
        for (int j = 0; j < 4; ++j)
            acc[i][j] = (fx4){0.f, 0.f, 0.f, 0.f};

    const int lane_off = col * 32 + ((quad ^ ((col >> 1) & 3)) << 3);
    const int aRow = wm * 128;
    const int bRow = wn * 64;

    for (int kb = 0; kb < NK; ++kb) {
        asm volatile("s_waitcnt vmcnt(0)" ::: "memory");
        __builtin_amdgcn_s_barrier();
        __builtin_amdgcn_sched_barrier(0);

        if (kb + 1 < NK) stage(kb + 1);

        const f16* P = &lds[kb & 1][0][0];
        f16x8 ah[8], bh[4];
#pragma unroll
        for (int nf = 0; nf < 4; ++nf)
            bh[nf] = *(const f16x8*)&P[8192 + (bRow + nf * 16) * 32 + lane_off];
#pragma unroll
        for (int mf = 0; mf < 8; ++mf)
            ah[mf] = *(const f16x8*)&P[(aRow + mf * 16) * 32 + lane_off];

        __builtin_amdgcn_s_setprio(1);
#pragma unroll
        for (int mf = 0; mf < 8; ++mf)
#pragma unroll
            for (int nf = 0; nf < 4; ++nf)
                acc[mf][nf] = __builtin_amdgcn_mfma_f32_16x16x32_f16(ah[mf], bh[nf], acc[mf][nf], 0, 0, 0);
        __builtin_amdgcn_s_setprio(0);
    }

#pragma unroll
    for (int mf = 0; mf < 8; ++mf)
#pragma unroll
        for (int nf = 0; nf < 4; ++nf) {
            const int n = nBase + wn * 64 + nf * 16 + col;
#pragma unroll
            for (int r = 0; r < 4; ++r) {
                const int m = mBase + wm * 128 + mf * 16 + quad * 4 + r;
                float v = acc[mf][nf][r] + bias_v[nf];
                size_t idx = (size_t)m * N + n;
                if constexpr (OUT == 2) {
                    Of[idx] = v;
                } else {
                    float t = tanhf(v);
                    Ohi[idx] = (f16)t;
                }
            }
        }
}

// ---------------- legacy 128x128 GEMM (L3: N=1024 -> 512 wgs) ----------------

template <int SPLIT, int OUT>
__global__ __launch_bounds__(256) void gemm_kernel(
    const f16* __restrict__ Hhi, const f16* __restrict__ Hlo,
    const f16* __restrict__ Whi, const f16* __restrict__ Wlo,
    const float* __restrict__ bias,
    f16* __restrict__ Ohi, f16* __restrict__ Olo, float* __restrict__ Of,
    int M, int N, int K)
{
    constexpr int LDSN = 128 * 32;
    __shared__ __align__(16) f16 Hs[(SPLIT ? 2 : 1) * LDSN];
    __shared__ __align__(16) f16 Ws[(SPLIT ? 2 : 1) * LDSN];

    const int tid  = threadIdx.x;
    const int lane = tid & 63;
    const int wave = tid >> 6;
    const int wm   = wave >> 1;
    const int wn   = wave & 1;
    const int col  = lane & 15;
    const int quad = lane >> 4;
    const int mBase = blockIdx.y * 128;
    const int nBase = blockIdx.x * 128;

    float bias_v[4];
#pragma unroll
    for (int nt = 0; nt < 4; ++nt)
        bias_v[nt] = bias[nBase + wn * 64 + nt * 16 + col];

    fx4 acc[4][4];
#pragma unroll
    for (int i = 0; i < 4; ++i)
#pragma unroll
        for (int j = 0; j < 4; ++j)
            acc[i][j] = (fx4){0.f, 0.f, 0.f, 0.f};

    const int c0 = wave * 128 + lane;

    for (int k0 = 0; k0 < K; k0 += 32) {
        __syncthreads();
#pragma unroll
        for (int i = 0; i < 2; ++i) {
            int c  = c0 + i * 64;
            int r  = c >> 2;
            int cc = c & 3;
            size_t gh = (size_t)(mBase + r) * K + k0 + cc * 8;
            size_t gw = (size_t)(nBase + r) * K + k0 + cc * 8;
            cp16(Hhi + gh, &Hs[c * 8]);
            cp16(Whi + gw, &Ws[c * 8]);
            if constexpr (SPLIT) {
                cp16(Hlo + gh, &Hs[LDSN + c * 8]);
                cp16(Wlo + gw, &Ws[LDSN + c * 8]);
            }
        }
        __syncthreads();

        f16x8 bh[4], bl[4];
#pragma unroll
        for (int nt = 0; nt < 4; ++nt) {
            int off = (wn * 64 + nt * 16 + col) * 32 + quad * 8;
            bh[nt] = *(const f16x8*)&Ws[off];
            if constexpr (SPLIT) bl[nt] = *(const f16x8*)&Ws[LDSN + off];
        }
#pragma unroll
        for (int mt = 0; mt < 4; ++mt) {
            int off = (wm * 64 + mt * 16 + col) * 32 + quad * 8;
            f16x8 ah = *(const f16x8*)&Hs[off];
            f16x8 al;
            if constexpr (SPLIT) al = *(const f16x8*)&Hs[LDSN + off];
#pragma unroll
            for (int nt = 0; nt < 4; ++nt) {
                acc[mt][nt] = __builtin_amdgcn_mfma_f32_16x16x32_f16(ah, bh[nt], acc[mt][nt], 0, 0, 0);
                if constexpr (SPLIT) {
                    acc[mt][nt] = __builtin_amdgcn_mfma_f32_16x16x32_f16(ah, bl[nt], acc[mt][nt], 0, 0, 0);
                    acc[mt][nt] = __builtin_amdgcn_mfma_f32_16x16x32_f16(al, bh[nt], acc[mt][nt], 0, 0, 0);
                }
            }
        }
    }

#pragma unroll
    for (int mt = 0; mt < 4; ++mt) {
#pragma unroll
        for (int nt = 0; nt < 4; ++nt) {
            int n = nBase + wn * 64 + nt * 16 + col;
#pragma unroll
            for (int r = 0; r < 4; ++r) {
                int m = mBase + wm * 64 + mt * 16 + quad * 4 + r;
                float v = acc[mt][nt][r] + bias_v[nt];
                size_t idx = (size_t)m * N + n;
                if constexpr (OUT == 2) {
                    Of[idx] = v;
                } else {
                    float t = tanhf(v);
                    f16 thi = (f16)t;
                    Ohi[idx] = thi;
                    if constexpr (OUT == 1) Olo[idx] = (f16)(t - (float)thi);
                }
            }
        }
    }
}

// ---------------- host ----------------

extern "C" void kernel_launch(void* const* d_in, const int* in_sizes, int n_in,
                              void* d_out, int out_size, void* d_ws, size_t ws_size,
                              hipStream_t stream) {
    const int BATCH = 8192;
    const int sizes[5] = {1024, 4096, 4096, 4096, 1024};

    char* ws = (char*)d_ws;
    f16*   x_hi  = (f16*)(ws + 0);
    f16*   x_lo  = (f16*)(ws + 16777216ULL);
    f16*   A0_hi = (f16*)(ws + 33554432ULL);
    f16*   A0_lo = (f16*)(ws + 41943040ULL);
    f16*   A_hi  = (f16*)(ws + 0);
    f16*   A_lo  = (f16*)(ws + 33554432ULL);
    f16*   H0_hi = (f16*)(ws + 67108864ULL);
    f16*   H0_lo = (f16*)(ws + 134217728ULL);
    f16*   H1_hi = (f16*)(ws + 201326592ULL);
    f16*   H2_hi = (f16*)(ws + 67108864ULL);   // alias H0_hi (free after L1)
    float* bb    = (float*)(ws + 268435456ULL);

    const float* x = (const float*)d_in[0];
    const float* p[4][6];
    for (int j = 0; j < 4; ++j)
        for (int t = 0; t < 6; ++t)
            p[j][t] = (const float*)d_in[1 + j * 6 + t];

    {
        int n = BATCH * sizes[0];
        split_x_kernel<<<n / 4 / 256, 256, 0, stream>>>(x, x_hi, x_lo, n);
    }

    // ---- layer 0: [8192,1024] @ [4096,1024]^T, 4-plane split, out hi+lo ----
    {
        int n = sizes[1] * sizes[0];
        prep_w_kernel<<<n / 4 / 256, 256, 0, stream>>>(p[0][0], p[0][1], p[0][2], A0_hi, A0_lo, n);
        prep_b_kernel<<<(sizes[1] + 255) / 256, 256, 0, stream>>>(p[0][3], p[0][4], p[0][5], bb, sizes[1]);
        dim3 grid(sizes[1] / 256, BATCH / 256);
        gemm256_split3_kernel<1><<<grid, 512, 0, stream>>>(
            x_hi, x_lo, A0_hi, A0_lo, bb, H0_hi, H0_lo, BATCH, sizes[1], sizes[0]);
    }

    // ---- layer 1: [8192,4096] @ [4096,4096]^T, 4-plane split, out hi ----
    {
        int n = sizes[2] * sizes[1];
        prep_w_kernel<<<n / 4 / 256, 256, 0, stream>>>(p[1][0], p[1][1], p[1][2], A_hi, A_lo, n);
        prep_b_kernel<<<(sizes[2] + 255) / 256, 256, 0, stream>>>(p[1][3], p[1][4], p[1][5], bb, sizes[2]);
        dim3 grid(sizes[2] / 256, BATCH / 256);
        gemm256_split3_kernel<0><<<grid, 512, 0, stream>>>(
            H0_hi, H0_lo, A_hi, A_lo, bb, H1_hi, nullptr, BATCH, sizes[2], sizes[1]);
    }

    // ---- layer 2: [8192,4096] @ [4096,4096]^T, single pass, out hi ----
    {
        int n = sizes[3] * sizes[2];
        prep_w_kernel<<<n / 4 / 256, 256, 0, stream>>>(p[2][0], p[2][1], p[2][2], A_hi, nullptr, n);
        prep_b_kernel<<<(sizes[3] + 255) / 256, 256, 0, stream>>>(p[2][3], p[2][4], p[2][5], bb, sizes[3]);
        dim3 grid(sizes[3] / 256, BATCH / 256);
        gemm256_ns_kernel<0><<<grid, 512, 0, stream>>>(
            H1_hi, A_hi, bb, H2_hi, nullptr, BATCH, sizes[3], sizes[2]);
    }

    // ---- layer 3: [8192,4096] @ [1024,4096]^T, single pass, fp32 out, no tanh ----
    {
        int n = sizes[4] * sizes[3];
        prep_w_kernel<<<n / 4 / 256, 256, 0, stream>>>(p[3][0], p[3][1], p[3][2], A_hi, nullptr, n);
        prep_b_kernel<<<(sizes[4] + 255) / 256, 256, 0, stream>>>(p[3][3], p[3][4], p[3][5], bb, sizes[4]);
        dim3 grid(sizes[4] / 128, BATCH / 128);
        gemm_kernel<0, 2><<<grid, 256, 0, stream>>>(
            H2_hi, nullptr, A_hi, nullptr, bb, nullptr, nullptr, (float*)d_out, BATCH, sizes[4], sizes[3]);
    }
}